// Round 12
// baseline (104.094 us; speedup 1.0000x reference)
//
#include <hip/hip_runtime.h>
#include <hip/hip_bf16.h>

#define BSZ 32
#define CIN 128
#define CD 64
#define HH 64
#define WW 64
#define PLANE (HH * WW)
#define NPIX (BSZ * HH * WW)
#define NB 8
#define BN_EPS 1e-5f

typedef __attribute__((ext_vector_type(8))) short short8v;
typedef __attribute__((ext_vector_type(4))) float f32x4;
typedef __attribute__((ext_vector_type(4))) unsigned int u32x4;

static __device__ __forceinline__ short f2bf(float f) {
    __hip_bfloat16 h = __float2bfloat16(f);
    return __builtin_bit_cast(short, h);
}
// packed bf16 convert: dst.lo16 = bf16(lo), dst.hi16 = bf16(hi) (RNE)
static __device__ __forceinline__ unsigned int cvtpk(float lo, float hi) {
    unsigned int r;
    asm("v_cvt_pk_bf16_f32 %0, %1, %2" : "=v"(r) : "v"(lo), "v"(hi));
    return r;
}
// closed-form uniform cubic B-spline 8-slot window (verified rounds 6-11)
static __device__ __forceinline__ u32x4 basisD(float v) {
    const float tt = (v + 2.2f) * 2.5f;
    const float fi = floorf(tt);
    const int i0 = (int)fi;
    const float u = tt - fi;
    const bool inr = (tt >= 0.0f) && (tt < 11.0f);
    const float u2 = u * u, u3 = u2 * u;
    const float t1 = 1.f - u;
    const float w0 = (1.f / 6.f) * t1 * t1 * t1;
    const float w3 = (1.f / 6.f) * u3;
    const float w1 = fmaf(0.5f, u3, 2.f / 3.f) - u2;
    const float w2 = 1.f - w0 - w1 - w3;
    const unsigned W01 = cvtpk(w0, w1);
    const unsigned W23 = cvtpk(w2, w3);
    const int q0 = i0 - 3;
    int a = q0 >> 1;
    const int bpar = q0 & 1;
    if (!inr) a = 100;
    const unsigned A1c = (W01 >> 16) | (W23 << 16);
    const unsigned C0 = bpar ? (W01 << 16) : W01;
    const unsigned C1 = bpar ? A1c : W23;
    const unsigned C2 = bpar ? (W23 >> 16) : 0u;
    u32x4 D;
    D.x = (a == 0) ? C0 : (a == -1) ? C1 : (a == -2) ? C2 : 0u;
    D.y = (a == 1) ? C0 : (a == 0) ? C1 : (a == -1) ? C2 : 0u;
    D.z = (a == 2) ? C0 : (a == 1) ? C1 : (a == 0) ? C2 : 0u;
    D.w = (a == 3) ? C0 : (a == 2) ? C1 : (a == 1) ? C2 : 0u;
    return D;
}
// rebuild tile0/tile1 bf16 A-frags from a [ch][17] (tile0,tile1)-pair pad
static __device__ __forceinline__ void gather_frags(
    const unsigned* __restrict__ pad, int s3, int hi, int m,
    short8v& f0, short8v& f1)
{
    unsigned q[8];
#pragma unroll
    for (int e = 0; e < 8; ++e) q[e] = pad[(s3 * 32 + 8 * hi + e) * 17 + m];
#pragma unroll
    for (int qi = 0; qi < 4; ++qi) {
        ((unsigned*)&f0)[qi] = (q[2 * qi] & 0xffffu) | (q[2 * qi + 1] << 16);
        ((unsigned*)&f1)[qi] = (q[2 * qi] >> 16) | (q[2 * qi + 1] & 0xffff0000u);
    }
}

// ---------------------------------------------------------------------------
// K0: prepack all matmul weights into MFMA B-fragment order (bf16) + fold BN.
// Fragment layout (verified round 2): element ((s*4+c)*64+l)*8+e holds
// W[k = s*32 + (l>>4)*8 + e][j = c*16 + (l&15)].
// ---------------------------------------------------------------------------
__global__ __launch_bounds__(256) void k_prep(
    const float* __restrict__ coef, const float* __restrict__ ssp,
    const float* __restrict__ sb, const float* __restrict__ f2w,
    const float* __restrict__ reduce_w, const float* __restrict__ g_w,
    const float* __restrict__ dw_g, const float* __restrict__ dw_beta,
    const float* __restrict__ dw_m, const float* __restrict__ dw_v,
    const float* __restrict__ dw_b, const float* __restrict__ g_g,
    const float* __restrict__ g_beta, const float* __restrict__ g_m,
    const float* __restrict__ g_v, const float* __restrict__ g_b,
    short* __restrict__ W1f, short* __restrict__ W2f,
    short* __restrict__ WRf, short* __restrict__ WGf,
    float* __restrict__ cbuf)
{
    const int idx = blockIdx.x * 256 + threadIdx.x;
    if (idx < 36864) {
        const int e = idx & 7, l = (idx >> 3) & 63, c = (idx >> 9) & 3, s = idx >> 11;
        const int k = s * 32 + ((l >> 4) << 3) + e;
        const int j = (c << 4) + (l & 15);
        float v;
        if (k < 512) {
            const int i = k >> 3, t = k & 7;
            v = coef[(i * 64 + j) * 8 + t] * ssp[i * 64 + j];
        } else {
            v = sb[(k - 512) * 64 + j];
        }
        W1f[idx] = f2bf(v);
    } else if (idx < 45056) {
        const int f = idx - 36864;
        const int e = f & 7, l = (f >> 3) & 63, c = (f >> 9) & 3, s = f >> 11;
        const int k = s * 32 + ((l >> 4) << 3) + e;
        const int j = (c << 4) + (l & 15);
        W2f[f] = f2bf(f2w[j * 64 + k]);
    } else if (idx < 53248) {
        const int f = idx - 45056;
        const int e = f & 7, l = (f >> 3) & 63, c = (f >> 9) & 3, s = f >> 11;
        const int k = s * 32 + ((l >> 4) << 3) + e;
        const int j = (c << 4) + (l & 15);
        WRf[f] = f2bf(reduce_w[j * CIN + k]);
    } else if (idx < 57344) {
        const int f = idx - 53248;
        const int e = f & 7, l = (f >> 3) & 63, c = (f >> 9) & 3, s = f >> 11;
        const int k = s * 32 + ((l >> 4) << 3) + e;
        const int j = (c << 4) + (l & 15);
        WGf[f] = f2bf(g_w[j * 64 + k]);
    } else if (idx < 57600) {
        const int q = (idx - 57344) >> 6, c = idx & 63;
        if (q == 0) cbuf[c] = dw_g[c] * rsqrtf(dw_v[c] + BN_EPS);
        else if (q == 1) {
            float sc = dw_g[c] * rsqrtf(dw_v[c] + BN_EPS);
            cbuf[64 + c] = (dw_b[c] - dw_m[c]) * sc + dw_beta[c];
        } else if (q == 2) cbuf[128 + c] = g_g[c] * rsqrtf(g_v[c] + BN_EPS);
        else {
            float sc = g_g[c] * rsqrtf(g_v[c] + BN_EPS);
            cbuf[192 + c] = (g_b[c] - g_m[c]) * sc + g_beta[c];
        }
    }
}

// ---------------------------------------------------------------------------
// K1: 1x1 conv 128->64 via MFMA. (unchanged from round 3)
// ---------------------------------------------------------------------------
__global__ __launch_bounds__(256) void k_reduce_mfma(
    const float* __restrict__ x, const short* __restrict__ WRf,
    const float* __restrict__ bias, float* __restrict__ out)
{
    __shared__ __align__(16) char smem[34048];
    short* As = (short*)smem;
    float* Osh = (float*)smem;
    const int bid = blockIdx.x;
    const int b = bid >> 5, h0 = (bid & 31) * 2;
    const int tid = threadIdx.x;
    const float* xb = x + (size_t)b * CIN * PLANE + h0 * WW;
#pragma unroll 1
    for (int p = 0; p < 64; ++p) {
        const int idx = tid + (p << 8);
        const int c = idx >> 7, rt = idx & 127;
        const float v = xb[(size_t)c * PLANE + rt];
        const int s = c >> 5, g = (c >> 3) & 3, e = c & 7;
        const int mt = rt >> 4, m = rt & 15;
        As[((mt * 4 + s) * 64 + (((g << 4) | m) ^ (s & 7))) * 8 + e] = f2bf(v);
    }
    __syncthreads();
    const int cw = tid >> 6, l = tid & 63;
    f32x4 acc[8];
#pragma unroll
    for (int i = 0; i < 8; ++i) acc[i] = (f32x4){0.f, 0.f, 0.f, 0.f};
#pragma unroll 1
    for (int s = 0; s < 4; ++s) {
        const short8v bfr = *(const short8v*)&WRf[((s * 4 + cw) * 64 + l) * 8];
        const int lx = l ^ (s & 7);
#pragma unroll
        for (int mt = 0; mt < 8; ++mt) {
            const short8v a = *(const short8v*)&As[((mt * 4 + s) * 64 + lx) * 8];
            acc[mt] = __builtin_amdgcn_mfma_f32_16x16x32_bf16(a, bfr, acc[mt], 0, 0, 0);
        }
    }
    __syncthreads();
    const int j = (cw << 4) + (l & 15);
    const float bj = bias[j];
    const int rb = (l >> 4) << 2;
#pragma unroll
    for (int mt = 0; mt < 8; ++mt)
#pragma unroll
        for (int r = 0; r < 4; ++r)
            Osh[j * 133 + mt * 16 + rb + r] = acc[mt][r] + bj;
    __syncthreads();
    float* ob = out + (size_t)b * CD * PLANE + h0 * WW;
#pragma unroll 1
    for (int p = 0; p < 32; ++p) {
        const int idx = tid + (p << 8);
        const int jj = idx >> 7, rt = idx & 127;
        ob[(size_t)jj * PLANE + rt] = Osh[jj * 133 + rt];
    }
}

// ---------------------------------------------------------------------------
// K2/K5: 7x7 depthwise conv, register-streaming, quarter-plane strips.
// (unchanged from round 6)
// ---------------------------------------------------------------------------
template<bool RESID>
__global__ __launch_bounds__(256) void k_dwconv(
    const float* __restrict__ in, const float* __restrict__ filt,
    const float* __restrict__ sc, const float* __restrict__ shv,
    const float* __restrict__ resid, float* __restrict__ out)
{
    const int bid = blockIdx.x;
    const int b = bid >> 6, c4 = (bid >> 2) & 15, strip = bid & 3;
    const int H0 = strip << 4;
    const int c = c4 * 4 + (threadIdx.x >> 6);
    const int lane = threadIdx.x & 63;
    const size_t pbase = ((size_t)b * CD + c) * PLANE;
    const float* plane = in + pbase;
    const float* wp = filt + c * 49;
    float K[49];
#pragma unroll
    for (int q = 0; q < 49; ++q) K[q] = wp[q];
    const float scl = RESID ? 1.f : sc[c];
    const float shf = shv[c];
    const float* rplane = RESID ? (resid + pbase) : nullptr;
    float* oplane = out + pbase;

    float acc[7] = {0.f, 0.f, 0.f, 0.f, 0.f, 0.f, 0.f};
#pragma unroll
    for (int rr = 0; rr < 22; ++rr) {
        const int ra = H0 + rr - 3;
        float rowv = 0.f;
        if (ra >= 0 && ra < 64) rowv = plane[ra * 64 + lane];
        float sh[7];
        sh[3] = rowv;
#pragma unroll
        for (int d = 1; d <= 3; ++d) {
            float tp = __shfl(rowv, lane + d);
            sh[3 + d] = (lane + d < 64) ? tp : 0.f;
            float tm = __shfl(rowv, lane - d);
            sh[3 - d] = (lane - d >= 0) ? tm : 0.f;
        }
#pragma unroll
        for (int dy = 0; dy < 7; ++dy) {
            const int o = rr - dy;
            if (o >= 0 && o < 16) {
                const int slot = o % 7;
#pragma unroll
                for (int dx = 0; dx < 7; ++dx)
                    acc[slot] = fmaf(sh[dx], K[dy * 7 + dx], acc[slot]);
            }
        }
        const int done = rr - 6;
        if (done >= 0 && done < 16) {
            const int slot = done % 7;
            const int h = H0 + done;
            float val;
            if (RESID) val = acc[slot] + shf + rplane[h * 64 + lane];
            else       val = acc[slot] * scl + shf;
            oplane[h * 64 + lane] = val;
            acc[slot] = 0.f;
        }
    }
}

// ---------------------------------------------------------------------------
// K3: fused KAN + f2 + gate + g-conv + BN via bf16 MFMA, NCHW -> NCHW.
// ROUND 12: round-6 block structure (measured best, 44.3us) with the stall
// chain cut down: (a) gate writes y as (tile0,tile1) cvtpk pairs into a
// stride-17 yPad; GEMM3 rebuilds A-frags via gather_frags; epilogue stores
// z DIRECTLY from C-layout (f32x4) — kills barriers B3/B5/B6 and both
// Ysh/Osh LDS round-trips (6 -> 2 barriers/tile); (b) GEMM1 fully unrolled
// so the 18 in-loop W1f L2 loads software-pipeline (VGPR free to grow: LDS
// 45.3KB caps occupancy at 3 blocks/CU regardless). Staging + fragment
// layouts byte-identical to round 6.
// ---------------------------------------------------------------------------
__global__ __launch_bounds__(256) void k_kan_fused(
    const float* __restrict__ xd, const short* __restrict__ W1f,
    const short* __restrict__ W2f, const short* __restrict__ WGf,
    const float* __restrict__ kb, const float* __restrict__ f2b,
    const float* __restrict__ gs, const float* __restrict__ gsh,
    float* __restrict__ z)
{
    __shared__ __align__(16) short As1[2 * 18 * 64 * 8];  // 36 KB
    __shared__ __align__(16) short As2[2 * 2 * 64 * 8];   //  4 KB
    __shared__ unsigned yPad[64 * 17];                    // 4.25 KB y pairs
    const int tid = threadIdx.x;
    const int tg0 = blockIdx.x * 32;
    const int bb = tg0 >> 12, pix0 = tg0 & 4095;
    const float* xb = xd + (size_t)bb * CD * PLANE + pix0;
    float* zb = z + (size_t)bb * CD * PLANE + pix0;
    const int tkn = tid & 31;
    const int w5 = tid >> 5;
    const int mt = tkn >> 4, m = tkn & 15;

    // ---- staging: basis + silu + v fragments (round-6 verified layout) ----
    float vf[8], sf[8];
#pragma unroll
    for (int p = 0; p < 8; ++p) {
        const int c = w5 * 8 + p;
        const float v = xb[(size_t)c * PLANE + tkn];
        vf[p] = v;
        sf[p] = v * __builtin_amdgcn_rcpf(1.0f + __expf(-v));
        const u32x4 D = basisD(v);
        const int s = w5 * 2 + (p >> 2);
        const int phys = (((p & 3) << 4) | m) ^ (s & 7);
        *(u32x4*)&As1[((mt * 18 + s) * 64 + phys) * 8] = D;
    }
    {   // silu + raw-v fragments: one b128 store each
        short8v vpk, spk;
#pragma unroll
        for (int q = 0; q < 4; ++q) {
            ((unsigned*)&vpk)[q] = cvtpk(vf[2 * q], vf[2 * q + 1]);
            ((unsigned*)&spk)[q] = cvtpk(sf[2 * q], sf[2 * q + 1]);
        }
        const int slot = ((w5 & 3) << 4) | m;
        const int s2 = 16 + (w5 >> 2);
        *(short8v*)&As1[((mt * 18 + s2) * 64 + (slot ^ (s2 & 7))) * 8] = spk;
        const int s3 = w5 >> 2;
        *(short8v*)&As2[((mt * 2 + s3) * 64 + (slot ^ (s3 & 7))) * 8] = vpk;
    }
    __syncthreads();   // B1: staging complete

    const int cw = tid >> 6, l = tid & 63;
    const int hi = l >> 4;
    const int j = (cw << 4) + (l & 15);
    const int mq = l & 15;
    const int rb = hi << 2;
    const float kbj = kb[j], f2bj = f2b[j];
    const float sj = gs[j], hj = gsh[j];

    // ---- GEMM1 (K=576, fully unrolled => W loads pipeline) + GEMM2 ----
    f32x4 accA0 = {0.f,0.f,0.f,0.f}, accA1 = {0.f,0.f,0.f,0.f};
    f32x4 accB0 = {0.f,0.f,0.f,0.f}, accB1 = {0.f,0.f,0.f,0.f};
#pragma unroll
    for (int s = 0; s < 18; ++s) {
        const short8v bfr = *(const short8v*)&W1f[((s * 4 + cw) * 64 + l) * 8];
        const short8v a0 = *(const short8v*)&As1[((0 * 18 + s) * 64 + (l ^ (s & 7))) * 8];
        const short8v a1 = *(const short8v*)&As1[((1 * 18 + s) * 64 + (l ^ (s & 7))) * 8];
        accA0 = __builtin_amdgcn_mfma_f32_16x16x32_bf16(a0, bfr, accA0, 0, 0, 0);
        accA1 = __builtin_amdgcn_mfma_f32_16x16x32_bf16(a1, bfr, accA1, 0, 0, 0);
    }
#pragma unroll
    for (int s = 0; s < 2; ++s) {
        const short8v bfr = *(const short8v*)&W2f[((s * 4 + cw) * 64 + l) * 8];
        const short8v a0 = *(const short8v*)&As2[((0 * 2 + s) * 64 + (l ^ s)) * 8];
        const short8v a1 = *(const short8v*)&As2[((1 * 2 + s) * 64 + (l ^ s)) * 8];
        accB0 = __builtin_amdgcn_mfma_f32_16x16x32_bf16(a0, bfr, accB0, 0, 0, 0);
        accB1 = __builtin_amdgcn_mfma_f32_16x16x32_bf16(a1, bfr, accB1, 0, 0, 0);
    }

    // ---- gate: y = (x1+kb)*(x2+f2b) -> (tile0,tile1) pairs into yPad ----
#pragma unroll
    for (int r = 0; r < 4; ++r) {
        const float ya = (accA0[r] + kbj) * (accB0[r] + f2bj);
        const float yb = (accA1[r] + kbj) * (accB1[r] + f2bj);
        yPad[j * 17 + rb + r] = cvtpk(ya, yb);
    }
    __syncthreads();   // B2: yPad complete (also: all GEMM LDS reads done)

    // ---- GEMM3: z = y @ g_w^T (A-frags gathered from yPad) ----
    f32x4 acc30 = {0.f,0.f,0.f,0.f}, acc31 = {0.f,0.f,0.f,0.f};
#pragma unroll
    for (int s3 = 0; s3 < 2; ++s3) {
        const short8v bfr = *(const short8v*)&WGf[((s3 * 4 + cw) * 64 + l) * 8];
        short8v f0, f1;
        gather_frags(yPad, s3, hi, mq, f0, f1);
        acc30 = __builtin_amdgcn_mfma_f32_16x16x32_bf16(f0, bfr, acc30, 0, 0, 0);
        acc31 = __builtin_amdgcn_mfma_f32_16x16x32_bf16(f1, bfr, acc31, 0, 0, 0);
    }

    // ---- epilogue: BN + direct NCHW stores from C-layout ----
    f32x4 o0, o1;
#pragma unroll
    for (int r = 0; r < 4; ++r) {
        o0[r] = acc30[r] * sj + hj;
        o1[r] = acc31[r] * sj + hj;
    }
    *(f32x4*)&zb[(size_t)j * PLANE + rb] = o0;
    *(f32x4*)&zb[(size_t)j * PLANE + 16 + rb] = o1;
}

// ---------------------------------------------------------------------------
extern "C" void kernel_launch(void* const* d_in, const int* in_sizes, int n_in,
                              void* d_out, int out_size, void* d_ws, size_t ws_size,
                              hipStream_t stream)
{
    (void)in_sizes; (void)n_in; (void)out_size; (void)ws_size;
    const float* x        = (const float*)d_in[0];
    const float* reduce_w = (const float*)d_in[1];
    const float* reduce_b = (const float*)d_in[2];
    const float* dw_w     = (const float*)d_in[3];
    const float* dw_b     = (const float*)d_in[4];
    const float* dw_g     = (const float*)d_in[5];
    const float* dw_beta  = (const float*)d_in[6];
    const float* dw_m     = (const float*)d_in[7];
    const float* dw_v     = (const float*)d_in[8];
    const float* f2_w     = (const float*)d_in[9];
    const float* f2_b     = (const float*)d_in[10];
    const float* coef     = (const float*)d_in[11];
    const float* sbase    = (const float*)d_in[12];
    const float* ssp      = (const float*)d_in[13];
    const float* kbias    = (const float*)d_in[14];
    const float* g_w      = (const float*)d_in[15];
    const float* g_b      = (const float*)d_in[16];
    const float* g_g      = (const float*)d_in[17];
    const float* g_beta   = (const float*)d_in[18];
    const float* g_m      = (const float*)d_in[19];
    const float* g_v      = (const float*)d_in[20];
    const float* dw2_w    = (const float*)d_in[21];
    const float* dw2_b    = (const float*)d_in[22];
    float* out = (float*)d_out;

    const size_t NEL = (size_t)BSZ * CD * PLANE;
    short* W1f = (short*)d_ws;
    short* W2f = W1f + 36864;
    short* WRf = W2f + 8192;
    short* WGf = WRf + 8192;
    float* cbuf = (float*)((char*)d_ws + 115200);
    float* inp = (float*)((char*)d_ws + 131072);
    float* xdb = inp + NEL;
    float* z   = xdb + NEL;

    k_prep<<<225, 256, 0, stream>>>(coef, ssp, sbase, f2_w, reduce_w, g_w,
                                    dw_g, dw_beta, dw_m, dw_v, dw_b,
                                    g_g, g_beta, g_m, g_v, g_b,
                                    W1f, W2f, WRf, WGf, cbuf);
    k_reduce_mfma<<<BSZ * 32, 256, 0, stream>>>(x, WRf, reduce_b, inp);
    k_dwconv<false><<<BSZ * 16 * 4, 256, 0, stream>>>(inp, dw_w, cbuf, cbuf + 64, nullptr, xdb);
    k_kan_fused<<<NPIX / 32, 256, 0, stream>>>(xdb, W1f, W2f, WGf, kbias, f2_b,
                                               cbuf + 128, cbuf + 192, z);
    k_dwconv<true><<<BSZ * 16 * 4, 256, 0, stream>>>(z, dw2_w, nullptr, dw2_b, inp, out);
}

// Round 13
// 103.299 us; speedup vs baseline: 1.0077x; 1.0077x over previous
//
#include <hip/hip_runtime.h>
#include <hip/hip_bf16.h>

#define BSZ 32
#define CIN 128
#define CD 64
#define HH 64
#define WW 64
#define PLANE (HH * WW)
#define NPIX (BSZ * HH * WW)
#define NB 8
#define BN_EPS 1e-5f

typedef __attribute__((ext_vector_type(8))) short short8v;
typedef __attribute__((ext_vector_type(4))) float f32x4;
typedef __attribute__((ext_vector_type(4))) unsigned int u32x4;

static __device__ __forceinline__ short f2bf(float f) {
    __hip_bfloat16 h = __float2bfloat16(f);
    return __builtin_bit_cast(short, h);
}
// packed bf16 convert: dst.lo16 = bf16(lo), dst.hi16 = bf16(hi) (RNE)
static __device__ __forceinline__ unsigned int cvtpk(float lo, float hi) {
    unsigned int r;
    asm("v_cvt_pk_bf16_f32 %0, %1, %2" : "=v"(r) : "v"(lo), "v"(hi));
    return r;
}
// closed-form uniform cubic B-spline 8-slot window.
// ROUND 13: placement via 64-bit funnel shift (~19 insts) instead of the
// 12-cmp/12-cndmask dword select (~34): D(128b) = P(64b=(w0,w1,w2,w3) bf16)
// shifted left by 16*q0 bits, q0 = i0-3 in [-3,7]. S1 = P<<(t&63) serves
// low word AND the t>=64 high word ((t-64)&63 == t&63); S2 = P>>((64-t)&63)
// serves the t<0 clip ((-t)&63 == (64-t)&63) AND the 0<t<64 carry-out.
// Weight math unchanged => output bit-identical to rounds 6-12.
static __device__ __forceinline__ u32x4 basisD(float v) {
    const float tt = (v + 2.2f) * 2.5f;
    const float fi = floorf(tt);
    const int i0 = (int)fi;
    const float u = tt - fi;
    const bool inr = (tt >= 0.0f) && (tt < 11.0f);
    const float u2 = u * u, u3 = u2 * u;
    const float t1 = 1.f - u;
    const float w0 = (1.f / 6.f) * t1 * t1 * t1;
    const float w3 = (1.f / 6.f) * u3;
    const float w1 = fmaf(0.5f, u3, 2.f / 3.f) - u2;
    const float w2 = 1.f - w0 - w1 - w3;
    unsigned W01 = cvtpk(w0, w1);
    unsigned W23 = cvtpk(w2, w3);
    if (!inr) { W01 = 0u; W23 = 0u; }            // OOB -> all-zero window
    const unsigned long long P =
        ((unsigned long long)W23 << 32) | (unsigned long long)W01;
    const int t = (i0 - 3) << 4;                 // bit offset, may be negative
    const unsigned long long S1 = P << (t & 63);
    const unsigned long long S2 = P >> ((64 - t) & 63);
    const bool c1 = (unsigned)t < 64u;           // 0 <= t < 64
    const bool c2 = t < 0;
    const bool c3 = t >= 64;
    const bool c5 = t > 0;
    const unsigned long long lo = c1 ? S1 : (c2 ? S2 : 0ULL);
    const unsigned long long hi = c3 ? S1 : ((c1 && c5) ? S2 : 0ULL);
    u32x4 D;
    D.x = (unsigned)lo;
    D.y = (unsigned)(lo >> 32);
    D.z = (unsigned)hi;
    D.w = (unsigned)(hi >> 32);
    return D;
}
// rebuild tile0/tile1 bf16 A-frags from a [ch][17] (tile0,tile1)-pair pad
static __device__ __forceinline__ void gather_frags(
    const unsigned* __restrict__ pad, int s3, int hi, int m,
    short8v& f0, short8v& f1)
{
    unsigned q[8];
#pragma unroll
    for (int e = 0; e < 8; ++e) q[e] = pad[(s3 * 32 + 8 * hi + e) * 17 + m];
#pragma unroll
    for (int qi = 0; qi < 4; ++qi) {
        ((unsigned*)&f0)[qi] = (q[2 * qi] & 0xffffu) | (q[2 * qi + 1] << 16);
        ((unsigned*)&f1)[qi] = (q[2 * qi] >> 16) | (q[2 * qi + 1] & 0xffff0000u);
    }
}

// ---------------------------------------------------------------------------
// K0: prepack all matmul weights into MFMA B-fragment order (bf16) + fold BN.
// Fragment layout (verified round 2): element ((s*4+c)*64+l)*8+e holds
// W[k = s*32 + (l>>4)*8 + e][j = c*16 + (l&15)].
// ---------------------------------------------------------------------------
__global__ __launch_bounds__(256) void k_prep(
    const float* __restrict__ coef, const float* __restrict__ ssp,
    const float* __restrict__ sb, const float* __restrict__ f2w,
    const float* __restrict__ reduce_w, const float* __restrict__ g_w,
    const float* __restrict__ dw_g, const float* __restrict__ dw_beta,
    const float* __restrict__ dw_m, const float* __restrict__ dw_v,
    const float* __restrict__ dw_b, const float* __restrict__ g_g,
    const float* __restrict__ g_beta, const float* __restrict__ g_m,
    const float* __restrict__ g_v, const float* __restrict__ g_b,
    short* __restrict__ W1f, short* __restrict__ W2f,
    short* __restrict__ WRf, short* __restrict__ WGf,
    float* __restrict__ cbuf)
{
    const int idx = blockIdx.x * 256 + threadIdx.x;
    if (idx < 36864) {
        const int e = idx & 7, l = (idx >> 3) & 63, c = (idx >> 9) & 3, s = idx >> 11;
        const int k = s * 32 + ((l >> 4) << 3) + e;
        const int j = (c << 4) + (l & 15);
        float v;
        if (k < 512) {
            const int i = k >> 3, t = k & 7;
            v = coef[(i * 64 + j) * 8 + t] * ssp[i * 64 + j];
        } else {
            v = sb[(k - 512) * 64 + j];
        }
        W1f[idx] = f2bf(v);
    } else if (idx < 45056) {
        const int f = idx - 36864;
        const int e = f & 7, l = (f >> 3) & 63, c = (f >> 9) & 3, s = f >> 11;
        const int k = s * 32 + ((l >> 4) << 3) + e;
        const int j = (c << 4) + (l & 15);
        W2f[f] = f2bf(f2w[j * 64 + k]);
    } else if (idx < 53248) {
        const int f = idx - 45056;
        const int e = f & 7, l = (f >> 3) & 63, c = (f >> 9) & 3, s = f >> 11;
        const int k = s * 32 + ((l >> 4) << 3) + e;
        const int j = (c << 4) + (l & 15);
        WRf[f] = f2bf(reduce_w[j * CIN + k]);
    } else if (idx < 57344) {
        const int f = idx - 53248;
        const int e = f & 7, l = (f >> 3) & 63, c = (f >> 9) & 3, s = f >> 11;
        const int k = s * 32 + ((l >> 4) << 3) + e;
        const int j = (c << 4) + (l & 15);
        WGf[f] = f2bf(g_w[j * 64 + k]);
    } else if (idx < 57600) {
        const int q = (idx - 57344) >> 6, c = idx & 63;
        if (q == 0) cbuf[c] = dw_g[c] * rsqrtf(dw_v[c] + BN_EPS);
        else if (q == 1) {
            float sc = dw_g[c] * rsqrtf(dw_v[c] + BN_EPS);
            cbuf[64 + c] = (dw_b[c] - dw_m[c]) * sc + dw_beta[c];
        } else if (q == 2) cbuf[128 + c] = g_g[c] * rsqrtf(g_v[c] + BN_EPS);
        else {
            float sc = g_g[c] * rsqrtf(g_v[c] + BN_EPS);
            cbuf[192 + c] = (g_b[c] - g_m[c]) * sc + g_beta[c];
        }
    }
}

// ---------------------------------------------------------------------------
// K1: 1x1 conv 128->64 via MFMA. (unchanged from round 3)
// ---------------------------------------------------------------------------
__global__ __launch_bounds__(256) void k_reduce_mfma(
    const float* __restrict__ x, const short* __restrict__ WRf,
    const float* __restrict__ bias, float* __restrict__ out)
{
    __shared__ __align__(16) char smem[34048];
    short* As = (short*)smem;
    float* Osh = (float*)smem;
    const int bid = blockIdx.x;
    const int b = bid >> 5, h0 = (bid & 31) * 2;
    const int tid = threadIdx.x;
    const float* xb = x + (size_t)b * CIN * PLANE + h0 * WW;
#pragma unroll 1
    for (int p = 0; p < 64; ++p) {
        const int idx = tid + (p << 8);
        const int c = idx >> 7, rt = idx & 127;
        const float v = xb[(size_t)c * PLANE + rt];
        const int s = c >> 5, g = (c >> 3) & 3, e = c & 7;
        const int mt = rt >> 4, m = rt & 15;
        As[((mt * 4 + s) * 64 + (((g << 4) | m) ^ (s & 7))) * 8 + e] = f2bf(v);
    }
    __syncthreads();
    const int cw = tid >> 6, l = tid & 63;
    f32x4 acc[8];
#pragma unroll
    for (int i = 0; i < 8; ++i) acc[i] = (f32x4){0.f, 0.f, 0.f, 0.f};
#pragma unroll 1
    for (int s = 0; s < 4; ++s) {
        const short8v bfr = *(const short8v*)&WRf[((s * 4 + cw) * 64 + l) * 8];
        const int lx = l ^ (s & 7);
#pragma unroll
        for (int mt = 0; mt < 8; ++mt) {
            const short8v a = *(const short8v*)&As[((mt * 4 + s) * 64 + lx) * 8];
            acc[mt] = __builtin_amdgcn_mfma_f32_16x16x32_bf16(a, bfr, acc[mt], 0, 0, 0);
        }
    }
    __syncthreads();
    const int j = (cw << 4) + (l & 15);
    const float bj = bias[j];
    const int rb = (l >> 4) << 2;
#pragma unroll
    for (int mt = 0; mt < 8; ++mt)
#pragma unroll
        for (int r = 0; r < 4; ++r)
            Osh[j * 133 + mt * 16 + rb + r] = acc[mt][r] + bj;
    __syncthreads();
    float* ob = out + (size_t)b * CD * PLANE + h0 * WW;
#pragma unroll 1
    for (int p = 0; p < 32; ++p) {
        const int idx = tid + (p << 8);
        const int jj = idx >> 7, rt = idx & 127;
        ob[(size_t)jj * PLANE + rt] = Osh[jj * 133 + rt];
    }
}

// ---------------------------------------------------------------------------
// K2/K5: 7x7 depthwise conv, register-streaming, quarter-plane strips.
// (unchanged from round 6)
// ---------------------------------------------------------------------------
template<bool RESID>
__global__ __launch_bounds__(256) void k_dwconv(
    const float* __restrict__ in, const float* __restrict__ filt,
    const float* __restrict__ sc, const float* __restrict__ shv,
    const float* __restrict__ resid, float* __restrict__ out)
{
    const int bid = blockIdx.x;
    const int b = bid >> 6, c4 = (bid >> 2) & 15, strip = bid & 3;
    const int H0 = strip << 4;
    const int c = c4 * 4 + (threadIdx.x >> 6);
    const int lane = threadIdx.x & 63;
    const size_t pbase = ((size_t)b * CD + c) * PLANE;
    const float* plane = in + pbase;
    const float* wp = filt + c * 49;
    float K[49];
#pragma unroll
    for (int q = 0; q < 49; ++q) K[q] = wp[q];
    const float scl = RESID ? 1.f : sc[c];
    const float shf = shv[c];
    const float* rplane = RESID ? (resid + pbase) : nullptr;
    float* oplane = out + pbase;

    float acc[7] = {0.f, 0.f, 0.f, 0.f, 0.f, 0.f, 0.f};
#pragma unroll
    for (int rr = 0; rr < 22; ++rr) {
        const int ra = H0 + rr - 3;
        float rowv = 0.f;
        if (ra >= 0 && ra < 64) rowv = plane[ra * 64 + lane];
        float sh[7];
        sh[3] = rowv;
#pragma unroll
        for (int d = 1; d <= 3; ++d) {
            float tp = __shfl(rowv, lane + d);
            sh[3 + d] = (lane + d < 64) ? tp : 0.f;
            float tm = __shfl(rowv, lane - d);
            sh[3 - d] = (lane - d >= 0) ? tm : 0.f;
        }
#pragma unroll
        for (int dy = 0; dy < 7; ++dy) {
            const int o = rr - dy;
            if (o >= 0 && o < 16) {
                const int slot = o % 7;
#pragma unroll
                for (int dx = 0; dx < 7; ++dx)
                    acc[slot] = fmaf(sh[dx], K[dy * 7 + dx], acc[slot]);
            }
        }
        const int done = rr - 6;
        if (done >= 0 && done < 16) {
            const int slot = done % 7;
            const int h = H0 + done;
            float val;
            if (RESID) val = acc[slot] + shf + rplane[h * 64 + lane];
            else       val = acc[slot] * scl + shf;
            oplane[h * 64 + lane] = val;
            acc[slot] = 0.f;
        }
    }
}

// ---------------------------------------------------------------------------
// K3: fused KAN + f2 + gate + g-conv + BN via bf16 MFMA, NCHW -> NCHW.
// ROUND 13: round-12 structure (2 barriers, yPad pair-gather GEMM3, direct
// C-layout z stores) with basisD's placement switched from 24-op dword
// select to the 64-bit funnel shift (see basisD comment). Everything else
// byte-identical to round 12.
// ---------------------------------------------------------------------------
__global__ __launch_bounds__(256) void k_kan_fused(
    const float* __restrict__ xd, const short* __restrict__ W1f,
    const short* __restrict__ W2f, const short* __restrict__ WGf,
    const float* __restrict__ kb, const float* __restrict__ f2b,
    const float* __restrict__ gs, const float* __restrict__ gsh,
    float* __restrict__ z)
{
    __shared__ __align__(16) short As1[2 * 18 * 64 * 8];  // 36 KB
    __shared__ __align__(16) short As2[2 * 2 * 64 * 8];   //  4 KB
    __shared__ unsigned yPad[64 * 17];                    // 4.25 KB y pairs
    const int tid = threadIdx.x;
    const int tg0 = blockIdx.x * 32;
    const int bb = tg0 >> 12, pix0 = tg0 & 4095;
    const float* xb = xd + (size_t)bb * CD * PLANE + pix0;
    float* zb = z + (size_t)bb * CD * PLANE + pix0;
    const int tkn = tid & 31;
    const int w5 = tid >> 5;
    const int mt = tkn >> 4, m = tkn & 15;

    // ---- staging: basis + silu + v fragments (round-6 verified layout) ----
    float vf[8], sf[8];
#pragma unroll
    for (int p = 0; p < 8; ++p) {
        const int c = w5 * 8 + p;
        const float v = xb[(size_t)c * PLANE + tkn];
        vf[p] = v;
        sf[p] = v * __builtin_amdgcn_rcpf(1.0f + __expf(-v));
        const u32x4 D = basisD(v);
        const int s = w5 * 2 + (p >> 2);
        const int phys = (((p & 3) << 4) | m) ^ (s & 7);
        *(u32x4*)&As1[((mt * 18 + s) * 64 + phys) * 8] = D;
    }
    {   // silu + raw-v fragments: one b128 store each
        short8v vpk, spk;
#pragma unroll
        for (int q = 0; q < 4; ++q) {
            ((unsigned*)&vpk)[q] = cvtpk(vf[2 * q], vf[2 * q + 1]);
            ((unsigned*)&spk)[q] = cvtpk(sf[2 * q], sf[2 * q + 1]);
        }
        const int slot = ((w5 & 3) << 4) | m;
        const int s2 = 16 + (w5 >> 2);
        *(short8v*)&As1[((mt * 18 + s2) * 64 + (slot ^ (s2 & 7))) * 8] = spk;
        const int s3 = w5 >> 2;
        *(short8v*)&As2[((mt * 2 + s3) * 64 + (slot ^ (s3 & 7))) * 8] = vpk;
    }
    __syncthreads();   // B1: staging complete

    const int cw = tid >> 6, l = tid & 63;
    const int hi = l >> 4;
    const int j = (cw << 4) + (l & 15);
    const int mq = l & 15;
    const int rb = hi << 2;
    const float kbj = kb[j], f2bj = f2b[j];
    const float sj = gs[j], hj = gsh[j];

    // ---- GEMM1 (K=576, fully unrolled => W loads pipeline) + GEMM2 ----
    f32x4 accA0 = {0.f,0.f,0.f,0.f}, accA1 = {0.f,0.f,0.f,0.f};
    f32x4 accB0 = {0.f,0.f,0.f,0.f}, accB1 = {0.f,0.f,0.f,0.f};
#pragma unroll
    for (int s = 0; s < 18; ++s) {
        const short8v bfr = *(const short8v*)&W1f[((s * 4 + cw) * 64 + l) * 8];
        const short8v a0 = *(const short8v*)&As1[((0 * 18 + s) * 64 + (l ^ (s & 7))) * 8];
        const short8v a1 = *(const short8v*)&As1[((1 * 18 + s) * 64 + (l ^ (s & 7))) * 8];
        accA0 = __builtin_amdgcn_mfma_f32_16x16x32_bf16(a0, bfr, accA0, 0, 0, 0);
        accA1 = __builtin_amdgcn_mfma_f32_16x16x32_bf16(a1, bfr, accA1, 0, 0, 0);
    }
#pragma unroll
    for (int s = 0; s < 2; ++s) {
        const short8v bfr = *(const short8v*)&W2f[((s * 4 + cw) * 64 + l) * 8];
        const short8v a0 = *(const short8v*)&As2[((0 * 2 + s) * 64 + (l ^ s)) * 8];
        const short8v a1 = *(const short8v*)&As2[((1 * 2 + s) * 64 + (l ^ s)) * 8];
        accB0 = __builtin_amdgcn_mfma_f32_16x16x32_bf16(a0, bfr, accB0, 0, 0, 0);
        accB1 = __builtin_amdgcn_mfma_f32_16x16x32_bf16(a1, bfr, accB1, 0, 0, 0);
    }

    // ---- gate: y = (x1+kb)*(x2+f2b) -> (tile0,tile1) pairs into yPad ----
#pragma unroll
    for (int r = 0; r < 4; ++r) {
        const float ya = (accA0[r] + kbj) * (accB0[r] + f2bj);
        const float yb = (accA1[r] + kbj) * (accB1[r] + f2bj);
        yPad[j * 17 + rb + r] = cvtpk(ya, yb);
    }
    __syncthreads();   // B2: yPad complete (also: all GEMM LDS reads done)

    // ---- GEMM3: z = y @ g_w^T (A-frags gathered from yPad) ----
    f32x4 acc30 = {0.f,0.f,0.f,0.f}, acc31 = {0.f,0.f,0.f,0.f};
#pragma unroll
    for (int s3 = 0; s3 < 2; ++s3) {
        const short8v bfr = *(const short8v*)&WGf[((s3 * 4 + cw) * 64 + l) * 8];
        short8v f0, f1;
        gather_frags(yPad, s3, hi, mq, f0, f1);
        acc30 = __builtin_amdgcn_mfma_f32_16x16x32_bf16(f0, bfr, acc30, 0, 0, 0);
        acc31 = __builtin_amdgcn_mfma_f32_16x16x32_bf16(f1, bfr, acc31, 0, 0, 0);
    }

    // ---- epilogue: BN + direct NCHW stores from C-layout ----
    f32x4 o0, o1;
#pragma unroll
    for (int r = 0; r < 4; ++r) {
        o0[r] = acc30[r] * sj + hj;
        o1[r] = acc31[r] * sj + hj;
    }
    *(f32x4*)&zb[(size_t)j * PLANE + rb] = o0;
    *(f32x4*)&zb[(size_t)j * PLANE + 16 + rb] = o1;
}

// ---------------------------------------------------------------------------
extern "C" void kernel_launch(void* const* d_in, const int* in_sizes, int n_in,
                              void* d_out, int out_size, void* d_ws, size_t ws_size,
                              hipStream_t stream)
{
    (void)in_sizes; (void)n_in; (void)out_size; (void)ws_size;
    const float* x        = (const float*)d_in[0];
    const float* reduce_w = (const float*)d_in[1];
    const float* reduce_b = (const float*)d_in[2];
    const float* dw_w     = (const float*)d_in[3];
    const float* dw_b     = (const float*)d_in[4];
    const float* dw_g     = (const float*)d_in[5];
    const float* dw_beta  = (const float*)d_in[6];
    const float* dw_m     = (const float*)d_in[7];
    const float* dw_v     = (const float*)d_in[8];
    const float* f2_w     = (const float*)d_in[9];
    const float* f2_b     = (const float*)d_in[10];
    const float* coef     = (const float*)d_in[11];
    const float* sbase    = (const float*)d_in[12];
    const float* ssp      = (const float*)d_in[13];
    const float* kbias    = (const float*)d_in[14];
    const float* g_w      = (const float*)d_in[15];
    const float* g_b      = (const float*)d_in[16];
    const float* g_g      = (const float*)d_in[17];
    const float* g_beta   = (const float*)d_in[18];
    const float* g_m      = (const float*)d_in[19];
    const float* g_v      = (const float*)d_in[20];
    const float* dw2_w    = (const float*)d_in[21];
    const float* dw2_b    = (const float*)d_in[22];
    float* out = (float*)d_out;

    const size_t NEL = (size_t)BSZ * CD * PLANE;
    short* W1f = (short*)d_ws;
    short* W2f = W1f + 36864;
    short* WRf = W2f + 8192;
    short* WGf = WRf + 8192;
    float* cbuf = (float*)((char*)d_ws + 115200);
    float* inp = (float*)((char*)d_ws + 131072);
    float* xdb = inp + NEL;
    float* z   = xdb + NEL;

    k_prep<<<225, 256, 0, stream>>>(coef, ssp, sbase, f2_w, reduce_w, g_w,
                                    dw_g, dw_beta, dw_m, dw_v, dw_b,
                                    g_g, g_beta, g_m, g_v, g_b,
                                    W1f, W2f, WRf, WGf, cbuf);
    k_reduce_mfma<<<BSZ * 32, 256, 0, stream>>>(x, WRf, reduce_b, inp);
    k_dwconv<false><<<BSZ * 16 * 4, 256, 0, stream>>>(inp, dw_w, cbuf, cbuf + 64, nullptr, xdb);
    k_kan_fused<<<NPIX / 32, 256, 0, stream>>>(xdb, W1f, W2f, WGf, kbias, f2_b,
                                               cbuf + 128, cbuf + 192, z);
    k_dwconv<true><<<BSZ * 16 * 4, 256, 0, stream>>>(z, dw2_w, nullptr, dw2_b, inp, out);
}